// Round 3
// baseline (557.179 us; speedup 1.0000x reference)
//
#include <hip/hip_runtime.h>
#include <math.h>

#define N_NODES 10000
#define N_EDGES 320000
#define IN_DIM  128
#define HID     256
#define CAP     128      // fixed bucket capacity; Poisson(32) => overflow prob ~0
#define NBLK    512      // cooperative grid: 2 blocks/CU, residency validated by runtime

typedef __attribute__((ext_vector_type(8))) short frag_ab;
typedef __attribute__((ext_vector_type(4))) float frag_cd;

// ---------------- workspace layout (bytes) ----------------
// yb     : N_NODES*64 u32       @ 0          (aggregated y, packed bf16x2)
// G      : 256*1024 f32         @ 2,560,000
// Wev    : 256*256 f32          @ 3,608,576
// WcT    : 256*64 u32           @ 3,870,720  (Wc^T, packed bf16x2 [n][k])
// bc     : 256 f32              @ 3,936,256
// rs     : N_NODES f32          @ 3,937,280
// xb     : N_NODES*64 u32       @ 3,977,280  (x, packed bf16x2)
// cursor : N_NODES i32          @ 6,537,280
// bar    : 4 i32                @ 6,577,280  (barrier counters; memset with cursor)
// bucket : N_NODES*CAP i32      @ 6,617,280

__device__ __forceinline__ unsigned bf16rne(float f) {
    union { float f; unsigned u; } c; c.f = f;
    return (c.u + 0x7FFFu + ((c.u >> 16) & 1u)) >> 16;
}
__device__ __forceinline__ float sig_f(float x)  { return 1.f / (1.f + __expf(-x)); }
__device__ __forceinline__ float tanh_f(float x) { return 1.f - 2.f / (1.f + __expf(2.f * x)); }

// Fast single-use grid barrier in workspace memory (counters pre-zeroed).
// Residency guaranteed by cooperative launch; agent-scope atomics execute at the
// device coherence point (m20: cross-XCD atomics work); __threadfence() provides
// the L2 writeback/invalidate release/acquire (proven by round-2 PASS).
__device__ __forceinline__ void gbar(int* c) {
    __syncthreads();                 // all block stores issued+drained (vmcnt0 at barrier)
    if (threadIdx.x == 0) {
        __threadfence();             // release: make this block's stores device-visible
        __hip_atomic_fetch_add(c, 1, __ATOMIC_ACQ_REL, __HIP_MEMORY_SCOPE_AGENT);
        while (__hip_atomic_load(c, __ATOMIC_ACQUIRE, __HIP_MEMORY_SCOPE_AGENT) < NBLK)
            __builtin_amdgcn_s_sleep(2);
        __threadfence();             // acquire: invalidate stale cached lines
    }
    __syncthreads();
}

__global__ __launch_bounds__(256, 2)
void k_fused(const float* __restrict__ x, const int* __restrict__ ei,
             const float* __restrict__ Wp, const float* __restrict__ bp,
             const float* __restrict__ wih, const float* __restrict__ whh,
             const float* __restrict__ b_ih, const float* __restrict__ b_hh,
             const float* __restrict__ iw, const float* __restrict__ b_gcn,
             float* __restrict__ out,
             unsigned* __restrict__ yb, float* __restrict__ G,
             float* __restrict__ Wev, unsigned* __restrict__ wct,
             float* __restrict__ bc, float* __restrict__ rs,
             unsigned* __restrict__ xb, int* __restrict__ cursor,
             int* __restrict__ bar, int* __restrict__ bucket) {
    __shared__ float smem[6144];     // 24 KB: gates staging (P0) / Wc arows (P2)
    const int bid = blockIdx.x;
    const int t = threadIdx.x;

    // ===== P0: gates GEMM (0..127) | x->bf16 (128..319) | bucket fill (320..511) =====
    if (bid < 128) {
        // G[256,1024] = iw[256,256] @ (W_ih + W_hh)^T ; 32m x 64n tiles, 2x4 micro
        int m0 = (bid & 7) * 32, n0 = (bid >> 3) * 64;
        float (*aT)[32] = (float(*)[32])smem;             // aT[kk][m]  [64][32]
        float (*bS)[64] = (float(*)[64])(smem + 2048);    // bS[kk][n]  [64][64]
        int tm = t & 15, tn = t >> 4;
        float acc[2][4] = {};
        for (int kt = 0; kt < 4; ++kt) {
            int k0 = kt * 64;
            {   // stage A: 32 rows x 16 float4
                int row = t >> 3;
                #pragma unroll
                for (int r = 0; r < 2; ++r) {
                    int kq = 2 * (t & 7) + r;
                    float4 av = *(const float4*)&iw[(m0 + row) * HID + k0 + 4 * kq];
                    aT[4 * kq + 0][row] = av.x; aT[4 * kq + 1][row] = av.y;
                    aT[4 * kq + 2][row] = av.z; aT[4 * kq + 3][row] = av.w;
                }
            }
            {   // stage B: 64 rows x 16 float4 (wih+whh)
                int row = t >> 2;
                #pragma unroll
                for (int r = 0; r < 4; ++r) {
                    int kq = 4 * (t & 3) + r;
                    float4 b1 = *(const float4*)&wih[(n0 + row) * HID + k0 + 4 * kq];
                    float4 b2 = *(const float4*)&whh[(n0 + row) * HID + k0 + 4 * kq];
                    bS[4 * kq + 0][row] = b1.x + b2.x; bS[4 * kq + 1][row] = b1.y + b2.y;
                    bS[4 * kq + 2][row] = b1.z + b2.z; bS[4 * kq + 3][row] = b1.w + b2.w;
                }
            }
            __syncthreads();
            #pragma unroll 8
            for (int kk = 0; kk < 64; ++kk) {
                float2 a2 = *(const float2*)&aT[kk][2 * tm];
                float4 b4 = *(const float4*)&bS[kk][4 * tn];
                float a[2] = {a2.x, a2.y};
                float b[4] = {b4.x, b4.y, b4.z, b4.w};
                #pragma unroll
                for (int i = 0; i < 2; ++i)
                    #pragma unroll
                    for (int j = 0; j < 4; ++j)
                        acc[i][j] = fmaf(a[i], b[j], acc[i][j]);
            }
            __syncthreads();
        }
        #pragma unroll
        for (int i = 0; i < 2; ++i) {
            float4 o = make_float4(acc[i][0], acc[i][1], acc[i][2], acc[i][3]);
            *(float4*)&G[(m0 + 2 * tm + i) * 1024 + n0 + 4 * tn] = o;
        }
    } else if (bid < 320) {
        // x -> packed bf16x2 (640,000 u32), strided over 192 blocks
        const float2* x2 = (const float2*)x;
        for (int idx = (bid - 128) * 256 + t; idx < N_NODES * 64; idx += 192 * 256) {
            float2 v = x2[idx];
            xb[idx] = bf16rne(v.x) | (bf16rne(v.y) << 16);
        }
    } else {
        // bucket fill: 192 blocks, grid-stride over 80000 int4 groups
        for (int u = (bid - 320) * 256 + t; u < N_EDGES / 4; u += 192 * 256) {
            int4 s4 = *(const int4*)&ei[u * 4];
            int4 d4 = *(const int4*)&ei[N_EDGES + u * 4];
            int p0 = atomicAdd(&cursor[d4.x], 1);
            if (p0 < CAP) bucket[d4.x * CAP + p0] = s4.x;
            int p1 = atomicAdd(&cursor[d4.y], 1);
            if (p1 < CAP) bucket[d4.y * CAP + p1] = s4.y;
            int p2 = atomicAdd(&cursor[d4.z], 1);
            if (p2 < CAP) bucket[d4.z * CAP + p2] = s4.z;
            int p3 = atomicAdd(&cursor[d4.w], 1);
            if (p3 < CAP) bucket[d4.w * CAP + p3] = s4.w;
        }
    }
    gbar(&bar[0]);

    // ===== P1: LSTM -> Wev (0..63, 4 rows each) | aggregation (64..511) =====
    if (bid < 64) {
        #pragma unroll
        for (int rr = 0; rr < 4; ++rr) {
            int r = bid * 4 + rr, j = t;
            float gi = G[r * 1024 + 0   + j] + b_ih[0   + j] + b_hh[0   + j];
            float gf = G[r * 1024 + 256 + j] + b_ih[256 + j] + b_hh[256 + j];
            float gg = G[r * 1024 + 512 + j] + b_ih[512 + j] + b_hh[512 + j];
            float go = G[r * 1024 + 768 + j] + b_ih[768 + j] + b_hh[768 + j];
            float c  = sig_f(gf) * iw[r * HID + j] + sig_f(gi) * tanh_f(gg);
            Wev[r * HID + j] = sig_f(go) * tanh_f(c);
        }
    } else {
        // aggregation; dinv computed on-the-fly from cursor
        int wv = t >> 6, lane = t & 63;
        for (int v = (bid - 64) * 4 + wv; v < N_NODES; v += 448 * 4) {
            int cntv = cursor[v];
            float dv = rsqrtf((float)(cntv + 1));
            int cnt = cntv > CAP ? CAP : cntv;
            unsigned self = xb[v * 64 + lane];
            union { unsigned u; float f; } c0, c1;
            c0.u = self << 16; c1.u = self & 0xFFFF0000u;
            float acc0 = dv * c0.f, acc1 = dv * c1.f;
            float wsum = dv;
            const int4* bkt4 = (const int4*)&bucket[v * CAP];
            int j = 0;
            for (; j + 4 <= cnt; j += 4) {
                int4 s = bkt4[j >> 2];
                float w0 = rsqrtf((float)(cursor[s.x] + 1));
                float w1 = rsqrtf((float)(cursor[s.y] + 1));
                float w2 = rsqrtf((float)(cursor[s.z] + 1));
                float w3 = rsqrtf((float)(cursor[s.w] + 1));
                unsigned r0 = xb[s.x * 64 + lane];
                unsigned r1 = xb[s.y * 64 + lane];
                unsigned r2 = xb[s.z * 64 + lane];
                unsigned r3 = xb[s.w * 64 + lane];
                union { unsigned u; float f; } a0, a1;
                a0.u = r0 << 16; a1.u = r0 & 0xFFFF0000u;
                acc0 = fmaf(w0, a0.f, acc0); acc1 = fmaf(w0, a1.f, acc1);
                a0.u = r1 << 16; a1.u = r1 & 0xFFFF0000u;
                acc0 = fmaf(w1, a0.f, acc0); acc1 = fmaf(w1, a1.f, acc1);
                a0.u = r2 << 16; a1.u = r2 & 0xFFFF0000u;
                acc0 = fmaf(w2, a0.f, acc0); acc1 = fmaf(w2, a1.f, acc1);
                a0.u = r3 << 16; a1.u = r3 & 0xFFFF0000u;
                acc0 = fmaf(w3, a0.f, acc0); acc1 = fmaf(w3, a1.f, acc1);
                wsum += w0 + w1 + w2 + w3;
            }
            for (; j < cnt; ++j) {
                int s = ((const int*)bkt4)[j];
                float w = rsqrtf((float)(cursor[s] + 1));
                unsigned r = xb[s * 64 + lane];
                union { unsigned u; float f; } a0, a1;
                a0.u = r << 16; a1.u = r & 0xFFFF0000u;
                acc0 = fmaf(w, a0.f, acc0); acc1 = fmaf(w, a1.f, acc1);
                wsum += w;
            }
            yb[v * 64 + lane] = bf16rne(dv * acc0) | (bf16rne(dv * acc1) << 16);
            if (lane == 0) rs[v] = dv * wsum;
        }
    }
    gbar(&bar[1]);

    // ===== P2: Wc GEMM -> wct (0..15) | bc (16) =====
    if (bid < 16) {
        // 8 rows of Wc^T per block: coalesced 16B bf16x8 writes, 8 FMA per Wev load
        int a0 = bid * 8;
        float (*ar)[HID] = (float(*)[HID])smem;   // [8][256] = 8 KB
        #pragma unroll
        for (int r = 0; r < 8; ++r) ar[r][t] = Wp[(a0 + r) * HID + t];
        __syncthreads();
        int j = t;
        float acc[8] = {};
        #pragma unroll 4
        for (int k = 0; k < HID; ++k) {
            float w = Wev[k * HID + j];
            #pragma unroll
            for (int r = 0; r < 8; ++r) acc[r] = fmaf(ar[r][k], w, acc[r]);
        }
        uint4 pv;
        pv.x = bf16rne(acc[0]) | (bf16rne(acc[1]) << 16);
        pv.y = bf16rne(acc[2]) | (bf16rne(acc[3]) << 16);
        pv.z = bf16rne(acc[4]) | (bf16rne(acc[5]) << 16);
        pv.w = bf16rne(acc[6]) | (bf16rne(acc[7]) << 16);
        *(uint4*)((unsigned short*)wct + j * IN_DIM + a0) = pv;
    } else if (bid == 16) {
        // bias row: bc[j] = sum_k bp[k] * Wev[k][j]
        smem[t] = bp[t];
        __syncthreads();
        float acc = 0.f;
        #pragma unroll 4
        for (int k = 0; k < HID; ++k)
            acc = fmaf(smem[k], Wev[k * HID + t], acc);
        bc[t] = acc;
    }
    gbar(&bar[2]);

    // ===== P3: out[10000,256] = yb @ WcT^T + rs*bc + b_gcn (bf16 MFMA) =====
    // 625 tiles of 16 rows, grid-strided; wave w covers n-tiles w,w+4,w+8,w+12
    {
        int w = t >> 6, lane = t & 63;
        int q = lane >> 4, ln = lane & 15;
        const int4* yb4  = (const int4*)yb;
        const int4* wct4 = (const int4*)wct;
        for (int tile = bid; tile < 625; tile += NBLK) {
            int m0 = tile * 16;
            union { int4 v; frag_ab f; } a[4];
            #pragma unroll
            for (int kc = 0; kc < 4; ++kc)
                a[kc].v = yb4[(m0 + ln) * 16 + kc * 4 + q];
            float rsv[4];
            #pragma unroll
            for (int r = 0; r < 4; ++r) rsv[r] = rs[m0 + q * 4 + r];
            #pragma unroll
            for (int i = 0; i < 4; ++i) {
                int n0 = (w + 4 * i) * 16;
                union { int4 v; frag_ab f; } b[4];
                #pragma unroll
                for (int kc = 0; kc < 4; ++kc)
                    b[kc].v = wct4[(n0 + ln) * 16 + kc * 4 + q];
                frag_cd acc = {0.f, 0.f, 0.f, 0.f};
                #pragma unroll
                for (int kc = 0; kc < 4; ++kc)
                    acc = __builtin_amdgcn_mfma_f32_16x16x32_bf16(a[kc].f, b[kc].f, acc, 0, 0, 0);
                int n = n0 + ln;
                float bcv = bc[n], bgv = b_gcn[n];
                #pragma unroll
                for (int r = 0; r < 4; ++r) {
                    int m = m0 + q * 4 + r;
                    out[m * HID + n] = acc[r] + rsv[r] * bcv + bgv;
                }
            }
        }
    }
}

extern "C" void kernel_launch(void* const* d_in, const int* in_sizes, int n_in,
                              void* d_out, int out_size, void* d_ws, size_t ws_size,
                              hipStream_t stream) {
    const float* x     = (const float*)d_in[0];
    const int*   ei    = (const int*)d_in[1];
    const float* Wp    = (const float*)d_in[2];
    const float* bp    = (const float*)d_in[3];
    const float* W_ih  = (const float*)d_in[4];
    const float* W_hh  = (const float*)d_in[5];
    const float* b_ih  = (const float*)d_in[6];
    const float* b_hh  = (const float*)d_in[7];
    const float* iw    = (const float*)d_in[8];
    const float* b_gcn = (const float*)d_in[9];
    float* out = (float*)d_out;

    char* ws = (char*)d_ws;
    unsigned* yb     = (unsigned*)(ws + 0);
    float*    G      = (float*)   (ws + 2560000);
    float*    Wev    = (float*)   (ws + 3608576);
    unsigned* wct    = (unsigned*)(ws + 3870720);
    float*    bc     = (float*)   (ws + 3936256);
    float*    rs     = (float*)   (ws + 3937280);
    unsigned* xb     = (unsigned*)(ws + 3977280);
    int*      cursor = (int*)     (ws + 6537280);
    int*      bar    = (int*)     (ws + 6577280);
    int*      bucket = (int*)     (ws + 6617280);

    // zero cursor (10000 ints) + barrier counters (4 ints) in one fill
    hipMemsetAsync(cursor, 0, N_NODES * sizeof(int) + 16, stream);

    void* args[] = {
        (void*)&x, (void*)&ei, (void*)&Wp, (void*)&bp, (void*)&W_ih, (void*)&W_hh,
        (void*)&b_ih, (void*)&b_hh, (void*)&iw, (void*)&b_gcn, (void*)&out,
        (void*)&yb, (void*)&G, (void*)&Wev, (void*)&wct, (void*)&bc, (void*)&rs,
        (void*)&xb, (void*)&cursor, (void*)&bar, (void*)&bucket
    };
    hipLaunchCooperativeKernel((const void*)k_fused, dim3(NBLK), dim3(256),
                               args, 0, stream);
}

// Round 4
// 232.054 us; speedup vs baseline: 2.4011x; 2.4011x over previous
//
#include <hip/hip_runtime.h>
#include <math.h>

#define N_NODES 10000
#define N_EDGES 320000
#define IN_DIM  128
#define HID     256
#define CAP     128      // bucket capacity; Poisson(32) => overflow prob ~0
#define NBLK    512      // cooperative grid (residency guarantee only; no grid barrier)
#define NWB     64       // W-path blocks (gates+LSTM+Wc, fully block-local)
#define NFB     (NBLK - NWB)   // 448 fill blocks

typedef __attribute__((ext_vector_type(8))) short frag_ab;
typedef __attribute__((ext_vector_type(4))) float frag_cd;

// ---------------- workspace layout (bytes) ----------------
// cursor @ 0       : 40,000   (in-degree counters, far-atomic)
// cnt    @ 40,000  : 16       (cnt[0]=fill arrivals, cnt[1]=wct arrivals; memset w/ cursor)
// wct    @ 40,064  : 65,536   (WcT packed bf16x2 [n=256][64], write-through)
// bc     @ 105,600 : 1,024    (bp @ Wev, write-through)
// bucket @ 106,624 : 5,120,000 (edge buckets, write-through)

__device__ __forceinline__ unsigned bf16rne(float f) {
    union { float f; unsigned u; } c; c.f = f;
    return (c.u + 0x7FFFu + ((c.u >> 16) & 1u)) >> 16;
}
__device__ __forceinline__ float sig_f(float x)  { return 1.f / (1.f + __expf(-x)); }
__device__ __forceinline__ float tanh_f(float x) { return 1.f - 2.f / (1.f + __expf(2.f * x)); }

// write-through stores: relaxed agent-scope atomic store -> device coherence point
// (same coherence class as device-scope atomicAdd, which is HW-verified cross-XCD).
__device__ __forceinline__ void wt_u32(unsigned* p, unsigned v) {
    __hip_atomic_store(p, v, __ATOMIC_RELAXED, __HIP_MEMORY_SCOPE_AGENT);
}
__device__ __forceinline__ void wt_f32(float* p, float v) {
    union { float f; unsigned u; } c; c.f = v;
    __hip_atomic_store((unsigned*)p, c.u, __ATOMIC_RELAXED, __HIP_MEMORY_SCOPE_AGENT);
}
// arrive: __syncthreads drains all the block's stores (compiler emits vmcnt(0)
// before s_barrier); write-through stores are then AT the coherence point.
__device__ __forceinline__ void arrive(int* c, int tid) {
    __syncthreads();
    if (tid == 0)
        __hip_atomic_fetch_add(c, 1, __ATOMIC_RELAXED, __HIP_MEMORY_SCOPE_AGENT);
}
// wait: relaxed far-atomic polling; NO cache-maintenance ops. Data read after this
// is fresh by first-touch (reader never cached those lines; LLC holds wt data).
__device__ __forceinline__ void waitflag(int* c, int n) {
    if (threadIdx.x == 0) {
        while (__hip_atomic_load(c, __ATOMIC_RELAXED, __HIP_MEMORY_SCOPE_AGENT) < n)
            __builtin_amdgcn_s_sleep(2);
    }
    __syncthreads();
    asm volatile("" ::: "memory");   // compiler barrier: no load hoisting above the flag
}

__global__ __launch_bounds__(256, 2)
void k_fused(const float* __restrict__ x, const int* __restrict__ ei,
             const float* __restrict__ Wp, const float* __restrict__ bp,
             const float* __restrict__ wih, const float* __restrict__ whh,
             const float* __restrict__ b_ih, const float* __restrict__ b_hh,
             const float* __restrict__ iw, const float* __restrict__ b_gcn,
             float* __restrict__ out,
             int* __restrict__ cursor, int* __restrict__ cnt,
             unsigned* __restrict__ wct, float* __restrict__ bc,
             int* __restrict__ bucket) {
    __shared__ __align__(16) char smem_raw[54784];   // 53.5 KB -> 2 blocks/CU (107/160 KB)
    const int bid = blockIdx.x;
    const int t = threadIdx.x;

    if (bid < NWB) {
        // ================= W-path: fully block-local gates->LSTM->Wc =================
        // Block b owns gate columns n_local = q*4+jj  <->  global n = q*256 + 4b + jj.
        float (*aT)[260]  = (float(*)[260])smem_raw;               // [32k][256m] staged iw^T
        float (*bSt)[20]  = (float(*)[20])(smem_raw + 33280);      // [256k][16n] Wih+Whh
        // --- stage B (once): bSt[k][n_local] = (Wih+Whh)[n_global][k] ---
        #pragma unroll
        for (int n = 0; n < 16; ++n) {
            int nrow = (n >> 2) * 256 + 4 * bid + (n & 3);
            bSt[t][n] = wih[nrow * 256 + t] + whh[nrow * 256 + t];
        }
        // --- gates GEMM: gates[256m][16n] = iw[256,256] @ Bsum^T, 4m x 4n / thread ---
        int mg = t >> 2, ng = t & 3;
        float acc[4][4] = {};
        for (int kt = 0; kt < 8; ++kt) {
            int k0 = kt * 32;
            __syncthreads();
            #pragma unroll
            for (int c = 0; c < 8; ++c) {     // stage aT[kk][m] = iw[m][k0+kk]
                float4 v = *(const float4*)&iw[t * 256 + k0 + 4 * c];
                aT[4 * c + 0][t] = v.x; aT[4 * c + 1][t] = v.y;
                aT[4 * c + 2][t] = v.z; aT[4 * c + 3][t] = v.w;
            }
            __syncthreads();
            #pragma unroll 4
            for (int kk = 0; kk < 32; ++kk) {
                float4 a4 = *(const float4*)&aT[kk][4 * mg];
                float4 b4 = *(const float4*)&bSt[k0 + kk][4 * ng];
                float a[4] = {a4.x, a4.y, a4.z, a4.w};
                float b[4] = {b4.x, b4.y, b4.z, b4.w};
                #pragma unroll
                for (int i = 0; i < 4; ++i)
                    #pragma unroll
                    for (int j = 0; j < 4; ++j)
                        acc[i][j] = fmaf(a[i], b[j], acc[i][j]);
            }
        }
        // --- gates -> LDS (reuse aT region) ---
        float (*gates_lds)[17] = (float(*)[17])smem_raw;           // [256][17]
        float (*wevc)[260]     = (float(*)[260])(smem_raw + 33280);// [4jj][256k] Wev cols
        __syncthreads();
        #pragma unroll
        for (int i = 0; i < 4; ++i)
            #pragma unroll
            for (int j = 0; j < 4; ++j)
                gates_lds[4 * mg + i][4 * ng + j] = acc[i][j];
        __syncthreads();
        // --- LSTM nonlinearity, thread r = t handles its row for all 4 owned cols ---
        {
            int r = t;
            #pragma unroll
            for (int jj = 0; jj < 4; ++jj) {
                int jcol = 4 * bid + jj;
                float gi = gates_lds[r][0  + jj] + b_ih[jcol]       + b_hh[jcol];
                float gf = gates_lds[r][4  + jj] + b_ih[256 + jcol] + b_hh[256 + jcol];
                float gg = gates_lds[r][8  + jj] + b_ih[512 + jcol] + b_hh[512 + jcol];
                float go = gates_lds[r][12 + jj] + b_ih[768 + jcol] + b_hh[768 + jcol];
                float c  = sig_f(gf) * iw[r * 256 + jcol] + sig_f(gi) * tanh_f(gg);
                wevc[jj][r] = sig_f(go) * tanh_f(c);
            }
        }
        __syncthreads();
        // --- Wc: wct[4b+jj][a-pair] = bf16x2( Wp[2a2..][k] . wevc[jj][k] ) ---
        {
            int a2 = t & 63, jj = t >> 6;
            float c0 = 0.f, c1 = 0.f;
            const float* p0 = &Wp[(2 * a2) * 256];
            const float* p1 = &Wp[(2 * a2 + 1) * 256];
            #pragma unroll 4
            for (int k4 = 0; k4 < 64; ++k4) {
                float4 w4 = *(const float4*)&wevc[jj][4 * k4];
                float4 q0 = *(const float4*)&p0[4 * k4];
                float4 q1 = *(const float4*)&p1[4 * k4];
                c0 = fmaf(q0.x, w4.x, fmaf(q0.y, w4.y, fmaf(q0.z, w4.z, fmaf(q0.w, w4.w, c0))));
                c1 = fmaf(q1.x, w4.x, fmaf(q1.y, w4.y, fmaf(q1.z, w4.z, fmaf(q1.w, w4.w, c1))));
            }
            wt_u32(&wct[(4 * bid + jj) * 64 + a2], bf16rne(c0) | (bf16rne(c1) << 16));
            if (t < 4) {   // bias column: bc[4b+t] = bp . wevc[t]
                float s = 0.f;
                for (int k4 = 0; k4 < 64; ++k4) {
                    float4 b4 = *(const float4*)&bp[4 * k4];
                    float4 w4 = *(const float4*)&wevc[t][4 * k4];
                    s = fmaf(b4.x, w4.x, fmaf(b4.y, w4.y, fmaf(b4.z, w4.z, fmaf(b4.w, w4.w, s))));
                }
                wt_f32(&bc[4 * bid + t], s);
            }
        }
        arrive(&cnt[1], t);
    } else {
        // ================= fill path: bucket CSR-ish build, write-through =================
        for (int u = (bid - NWB) * 256 + t; u < N_EDGES / 4; u += NFB * 256) {
            int4 s4 = *(const int4*)&ei[u * 4];
            int4 d4 = *(const int4*)&ei[N_EDGES + u * 4];
            int p0 = atomicAdd(&cursor[d4.x], 1);
            if (p0 < CAP) wt_u32((unsigned*)&bucket[d4.x * CAP + p0], (unsigned)s4.x);
            int p1 = atomicAdd(&cursor[d4.y], 1);
            if (p1 < CAP) wt_u32((unsigned*)&bucket[d4.y * CAP + p1], (unsigned)s4.y);
            int p2 = atomicAdd(&cursor[d4.z], 1);
            if (p2 < CAP) wt_u32((unsigned*)&bucket[d4.z * CAP + p2], (unsigned)s4.z);
            int p3 = atomicAdd(&cursor[d4.w], 1);
            if (p3 < CAP) wt_u32((unsigned*)&bucket[d4.w * CAP + p3], (unsigned)s4.w);
        }
        arrive(&cnt[0], t);
    }

    // ================= P1: per-tile agg (fp32 from x) + MFMA out =================
    waitflag(&cnt[0], NFB);                       // buckets/cursor final
    unsigned (*y_lds)[64] = (unsigned(*)[64])smem_raw;   // [16][64] bf16x2
    float* rs_lds = (float*)(smem_raw + 4096);
    const float2* x2 = (const float2*)x;
    const int4* wct4 = (const int4*)wct;
    int w = t >> 6, lane = t & 63;
    int q = lane >> 4, ln = lane & 15;
    bool wctReady = false;

    for (int tile = (NBLK - 1 - bid); tile < 625; tile += NBLK) {
        __syncthreads();                          // y_lds reuse guard
        // --- aggregate 16 nodes (4 per wave), fp32 gathers from x ---
        for (int vi = 0; vi < 4; ++vi) {
            int r = vi * 4 + w;
            int v = tile * 16 + r;
            int cntv = cursor[v];
            float dv = rsqrtf((float)(cntv + 1));
            int cnt2 = cntv > CAP ? CAP : cntv;
            float2 sv = x2[v * 64 + lane];
            float acc0 = dv * sv.x, acc1 = dv * sv.y, wsum = dv;
            const int4* bkt4 = (const int4*)&bucket[v * CAP];
            int j = 0;
            for (; j + 4 <= cnt2; j += 4) {
                int4 s = bkt4[j >> 2];
                float w0 = rsqrtf((float)(cursor[s.x] + 1));
                float w1 = rsqrtf((float)(cursor[s.y] + 1));
                float w2 = rsqrtf((float)(cursor[s.z] + 1));
                float w3 = rsqrtf((float)(cursor[s.w] + 1));
                float2 r0 = x2[s.x * 64 + lane];
                float2 r1 = x2[s.y * 64 + lane];
                float2 r2 = x2[s.z * 64 + lane];
                float2 r3 = x2[s.w * 64 + lane];
                acc0 = fmaf(w0, r0.x, acc0); acc1 = fmaf(w0, r0.y, acc1);
                acc0 = fmaf(w1, r1.x, acc0); acc1 = fmaf(w1, r1.y, acc1);
                acc0 = fmaf(w2, r2.x, acc0); acc1 = fmaf(w2, r2.y, acc1);
                acc0 = fmaf(w3, r3.x, acc0); acc1 = fmaf(w3, r3.y, acc1);
                wsum += w0 + w1 + w2 + w3;
            }
            for (; j < cnt2; ++j) {
                int s = bucket[v * CAP + j];
                float ws = rsqrtf((float)(cursor[s] + 1));
                float2 rv = x2[s * 64 + lane];
                acc0 = fmaf(ws, rv.x, acc0); acc1 = fmaf(ws, rv.y, acc1);
                wsum += ws;
            }
            y_lds[r][lane] = bf16rne(dv * acc0) | (bf16rne(dv * acc1) << 16);
            if (lane == 0) rs_lds[r] = dv * wsum;
        }
        if (!wctReady) { waitflag(&cnt[1], NWB); wctReady = true; }
        else __syncthreads();
        // --- MFMA: out_tile[16,256] = y @ WcT^T + rs*bc + b_gcn ---
        union { int4 v; frag_ab f; } a[4];
        const int4* ya = (const int4*)&y_lds[0][0];
        #pragma unroll
        for (int kc = 0; kc < 4; ++kc)
            a[kc].v = ya[ln * 16 + kc * 4 + q];
        float rsv[4];
        #pragma unroll
        for (int r = 0; r < 4; ++r) rsv[r] = rs_lds[q * 4 + r];
        #pragma unroll
        for (int i = 0; i < 4; ++i) {
            int n0 = (w + 4 * i) * 16;
            union { int4 v; frag_ab f; } b[4];
            #pragma unroll
            for (int kc = 0; kc < 4; ++kc)
                b[kc].v = wct4[(n0 + ln) * 16 + kc * 4 + q];
            frag_cd accd = {0.f, 0.f, 0.f, 0.f};
            #pragma unroll
            for (int kc = 0; kc < 4; ++kc)
                accd = __builtin_amdgcn_mfma_f32_16x16x32_bf16(a[kc].f, b[kc].f, accd, 0, 0, 0);
            int n = n0 + ln;
            float bcv = bc[n], bgv = b_gcn[n];
            #pragma unroll
            for (int r = 0; r < 4; ++r) {
                int m = tile * 16 + q * 4 + r;
                out[m * HID + n] = accd[r] + rsv[r] * bcv + bgv;
            }
        }
    }
}

extern "C" void kernel_launch(void* const* d_in, const int* in_sizes, int n_in,
                              void* d_out, int out_size, void* d_ws, size_t ws_size,
                              hipStream_t stream) {
    const float* x     = (const float*)d_in[0];
    const int*   ei    = (const int*)d_in[1];
    const float* Wp    = (const float*)d_in[2];
    const float* bp    = (const float*)d_in[3];
    const float* W_ih  = (const float*)d_in[4];
    const float* W_hh  = (const float*)d_in[5];
    const float* b_ih  = (const float*)d_in[6];
    const float* b_hh  = (const float*)d_in[7];
    const float* iw    = (const float*)d_in[8];
    const float* b_gcn = (const float*)d_in[9];
    float* out = (float*)d_out;

    char* ws = (char*)d_ws;
    int*      cursor = (int*)     (ws + 0);
    int*      cnt    = (int*)     (ws + 40000);
    unsigned* wct    = (unsigned*)(ws + 40064);
    float*    bc     = (float*)   (ws + 105600);
    int*      bucket = (int*)     (ws + 106624);

    // zero cursor (10000 ints) + flag counters (4 ints) in one fill
    hipMemsetAsync(cursor, 0, 40016, stream);

    void* args[] = {
        (void*)&x, (void*)&ei, (void*)&Wp, (void*)&bp, (void*)&W_ih, (void*)&W_hh,
        (void*)&b_ih, (void*)&b_hh, (void*)&iw, (void*)&b_gcn, (void*)&out,
        (void*)&cursor, (void*)&cnt, (void*)&wct, (void*)&bc, (void*)&bucket
    };
    hipLaunchCooperativeKernel((const void*)k_fused, dim3(NBLK), dim3(256),
                               args, 0, stream);
}

// Round 5
// 161.702 us; speedup vs baseline: 3.4457x; 1.4351x over previous
//
#include <hip/hip_runtime.h>
#include <math.h>

#define N_NODES 10000
#define N_EDGES 320000
#define IN_DIM  128
#define HID     256
#define CAP     128      // bucket capacity; Poisson(32) => overflow prob ~0
#define NB1     512      // K1 grid: 64 W-path blocks + 448 fill blocks
#define NWB     64
#define NFB     (NB1 - NWB)

typedef __attribute__((ext_vector_type(8))) short frag_ab;
typedef __attribute__((ext_vector_type(4))) float frag_cd;

// ---------------- workspace layout (bytes) ----------------
// cursor @ 0       : 40,000    (in-degree counters, atomicAdd)
// wct    @ 40,064  : 65,536    (WcT packed bf16x2 [n=256][64])
// bc     @ 105,600 : 1,024     (bp @ Wev)
// bucket @ 106,624 : 5,120,000 (edge buckets)

__device__ __forceinline__ unsigned bf16rne(float f) {
    union { float f; unsigned u; } c; c.f = f;
    return (c.u + 0x7FFFu + ((c.u >> 16) & 1u)) >> 16;
}
__device__ __forceinline__ float sig_f(float x)  { return 1.f / (1.f + __expf(-x)); }
__device__ __forceinline__ float tanh_f(float x) { return 1.f - 2.f / (1.f + __expf(2.f * x)); }

// ===== K1: W-path (blocks 0..63, fully block-local) | bucket fill (64..511) =====
__global__ __launch_bounds__(256, 2)
void k1_prep(const int* __restrict__ ei,
             const float* __restrict__ Wp, const float* __restrict__ bp,
             const float* __restrict__ wih, const float* __restrict__ whh,
             const float* __restrict__ b_ih, const float* __restrict__ b_hh,
             const float* __restrict__ iw,
             int* __restrict__ cursor, unsigned* __restrict__ wct,
             float* __restrict__ bc, int* __restrict__ bucket) {
    __shared__ __align__(16) char smem_raw[54784];   // 53.5 KB, W-path blocks only
    const int bid = blockIdx.x;
    const int t = threadIdx.x;

    if (bid < NWB) {
        // Block b owns gate columns n_local = q*4+jj  <->  global n = q*256 + 4b + jj.
        float (*aT)[260]  = (float(*)[260])smem_raw;               // [32k][256m] staged iw^T
        float (*bSt)[20]  = (float(*)[20])(smem_raw + 33280);      // [256k][16n] Wih+Whh
        #pragma unroll
        for (int n = 0; n < 16; ++n) {
            int nrow = (n >> 2) * 256 + 4 * bid + (n & 3);
            bSt[t][n] = wih[nrow * 256 + t] + whh[nrow * 256 + t];
        }
        // gates GEMM: gates[256m][16n] = iw[256,256] @ Bsum^T, 4m x 4n / thread
        int mg = t >> 2, ng = t & 3;
        float acc[4][4] = {};
        for (int kt = 0; kt < 8; ++kt) {
            int k0 = kt * 32;
            __syncthreads();
            #pragma unroll
            for (int c = 0; c < 8; ++c) {     // stage aT[kk][m] = iw[m][k0+kk]
                float4 v = *(const float4*)&iw[t * 256 + k0 + 4 * c];
                aT[4 * c + 0][t] = v.x; aT[4 * c + 1][t] = v.y;
                aT[4 * c + 2][t] = v.z; aT[4 * c + 3][t] = v.w;
            }
            __syncthreads();
            #pragma unroll 4
            for (int kk = 0; kk < 32; ++kk) {
                float4 a4 = *(const float4*)&aT[kk][4 * mg];
                float4 b4 = *(const float4*)&bSt[k0 + kk][4 * ng];
                float a[4] = {a4.x, a4.y, a4.z, a4.w};
                float b[4] = {b4.x, b4.y, b4.z, b4.w};
                #pragma unroll
                for (int i = 0; i < 4; ++i)
                    #pragma unroll
                    for (int j = 0; j < 4; ++j)
                        acc[i][j] = fmaf(a[i], b[j], acc[i][j]);
            }
        }
        // gates -> LDS (reuse aT region)
        float (*gates_lds)[17] = (float(*)[17])smem_raw;           // [256][17]
        float (*wevc)[260]     = (float(*)[260])(smem_raw + 33280);// [4jj][256k] Wev cols
        __syncthreads();
        #pragma unroll
        for (int i = 0; i < 4; ++i)
            #pragma unroll
            for (int j = 0; j < 4; ++j)
                gates_lds[4 * mg + i][4 * ng + j] = acc[i][j];
        __syncthreads();
        // LSTM nonlinearity: thread r = t, all 4 owned columns
        {
            int r = t;
            #pragma unroll
            for (int jj = 0; jj < 4; ++jj) {
                int jcol = 4 * bid + jj;
                float gi = gates_lds[r][0  + jj] + b_ih[jcol]       + b_hh[jcol];
                float gf = gates_lds[r][4  + jj] + b_ih[256 + jcol] + b_hh[256 + jcol];
                float gg = gates_lds[r][8  + jj] + b_ih[512 + jcol] + b_hh[512 + jcol];
                float go = gates_lds[r][12 + jj] + b_ih[768 + jcol] + b_hh[768 + jcol];
                float c  = sig_f(gf) * iw[r * 256 + jcol] + sig_f(gi) * tanh_f(gg);
                wevc[jj][r] = sig_f(go) * tanh_f(c);
            }
        }
        __syncthreads();
        // Wc: wct[4b+jj][a2] = bf16x2( Wp[2a2][.].wevc[jj], Wp[2a2+1][.].wevc[jj] )
        {
            int a2 = t & 63, jj = t >> 6;
            float c0 = 0.f, c1 = 0.f;
            const float* p0 = &Wp[(2 * a2) * 256];
            const float* p1 = &Wp[(2 * a2 + 1) * 256];
            #pragma unroll 4
            for (int k4 = 0; k4 < 64; ++k4) {
                float4 w4 = *(const float4*)&wevc[jj][4 * k4];
                float4 q0 = *(const float4*)&p0[4 * k4];
                float4 q1 = *(const float4*)&p1[4 * k4];
                c0 = fmaf(q0.x, w4.x, fmaf(q0.y, w4.y, fmaf(q0.z, w4.z, fmaf(q0.w, w4.w, c0))));
                c1 = fmaf(q1.x, w4.x, fmaf(q1.y, w4.y, fmaf(q1.z, w4.z, fmaf(q1.w, w4.w, c1))));
            }
            wct[(4 * bid + jj) * 64 + a2] = bf16rne(c0) | (bf16rne(c1) << 16);
            if (t < 4) {   // bias column: bc[4b+t] = bp . wevc[t]
                float s = 0.f;
                for (int k4 = 0; k4 < 64; ++k4) {
                    float4 b4 = *(const float4*)&bp[4 * k4];
                    float4 w4 = *(const float4*)&wevc[t][4 * k4];
                    s = fmaf(b4.x, w4.x, fmaf(b4.y, w4.y, fmaf(b4.z, w4.z, fmaf(b4.w, w4.w, s))));
                }
                bc[4 * bid + t] = s;
            }
        }
    } else {
        // bucket fill: 448 blocks, grid-stride over 80000 int4 groups
        for (int u = (bid - NWB) * 256 + t; u < N_EDGES / 4; u += NFB * 256) {
            int4 s4 = *(const int4*)&ei[u * 4];
            int4 d4 = *(const int4*)&ei[N_EDGES + u * 4];
            int p0 = atomicAdd(&cursor[d4.x], 1);
            if (p0 < CAP) bucket[d4.x * CAP + p0] = s4.x;
            int p1 = atomicAdd(&cursor[d4.y], 1);
            if (p1 < CAP) bucket[d4.y * CAP + p1] = s4.y;
            int p2 = atomicAdd(&cursor[d4.z], 1);
            if (p2 < CAP) bucket[d4.z * CAP + p2] = s4.z;
            int p3 = atomicAdd(&cursor[d4.w], 1);
            if (p3 < CAP) bucket[d4.w * CAP + p3] = s4.w;
        }
    }
}

// ===== K2: per-tile aggregation (fp32 gathers from x) + MFMA out =====
// 625 blocks x 256; block = one 16-row m-tile. Small LDS -> high occupancy/TLP.
__global__ __launch_bounds__(256)
void k2_agg_out(const float* __restrict__ x, const int* __restrict__ cursor,
                const int* __restrict__ bucket, const unsigned* __restrict__ wct,
                const float* __restrict__ bc, const float* __restrict__ b_gcn,
                float* __restrict__ out) {
    __shared__ unsigned y_lds[16][64];   // bf16x2 rows
    __shared__ float rs_lds[16];
    const int t = threadIdx.x;
    const int tile = blockIdx.x;
    const int w = t >> 6, lane = t & 63;
    const int q = lane >> 4, ln = lane & 15;
    const float2* x2 = (const float2*)x;

    // --- aggregate 16 nodes (4 sequential per wave), 8-wide unrolled gather ---
    for (int vi = 0; vi < 4; ++vi) {
        int r = vi * 4 + w;
        int v = tile * 16 + r;
        int cntv = cursor[v];
        float dv = rsqrtf((float)(cntv + 1));
        int cnt2 = cntv > CAP ? CAP : cntv;
        float2 sv = x2[v * 64 + lane];
        float acc0 = dv * sv.x, acc1 = dv * sv.y, wsum = dv;
        const int4* bkt4 = (const int4*)&bucket[v * CAP];
        int j = 0;
        for (; j + 8 <= cnt2; j += 8) {
            int4 sa = bkt4[j >> 2];
            int4 sb = bkt4[(j >> 2) + 1];
            float w0 = rsqrtf((float)(cursor[sa.x] + 1));
            float w1 = rsqrtf((float)(cursor[sa.y] + 1));
            float w2 = rsqrtf((float)(cursor[sa.z] + 1));
            float w3 = rsqrtf((float)(cursor[sa.w] + 1));
            float w4 = rsqrtf((float)(cursor[sb.x] + 1));
            float w5 = rsqrtf((float)(cursor[sb.y] + 1));
            float w6 = rsqrtf((float)(cursor[sb.z] + 1));
            float w7 = rsqrtf((float)(cursor[sb.w] + 1));
            float2 r0 = x2[sa.x * 64 + lane];
            float2 r1 = x2[sa.y * 64 + lane];
            float2 r2 = x2[sa.z * 64 + lane];
            float2 r3 = x2[sa.w * 64 + lane];
            float2 r4 = x2[sb.x * 64 + lane];
            float2 r5 = x2[sb.y * 64 + lane];
            float2 r6 = x2[sb.z * 64 + lane];
            float2 r7 = x2[sb.w * 64 + lane];
            acc0 = fmaf(w0, r0.x, acc0); acc1 = fmaf(w0, r0.y, acc1);
            acc0 = fmaf(w1, r1.x, acc0); acc1 = fmaf(w1, r1.y, acc1);
            acc0 = fmaf(w2, r2.x, acc0); acc1 = fmaf(w2, r2.y, acc1);
            acc0 = fmaf(w3, r3.x, acc0); acc1 = fmaf(w3, r3.y, acc1);
            acc0 = fmaf(w4, r4.x, acc0); acc1 = fmaf(w4, r4.y, acc1);
            acc0 = fmaf(w5, r5.x, acc0); acc1 = fmaf(w5, r5.y, acc1);
            acc0 = fmaf(w6, r6.x, acc0); acc1 = fmaf(w6, r6.y, acc1);
            acc0 = fmaf(w7, r7.x, acc0); acc1 = fmaf(w7, r7.y, acc1);
            wsum += w0 + w1 + w2 + w3 + w4 + w5 + w6 + w7;
        }
        for (; j < cnt2; ++j) {
            int s = bucket[v * CAP + j];
            float ws = rsqrtf((float)(cursor[s] + 1));
            float2 rv = x2[s * 64 + lane];
            acc0 = fmaf(ws, rv.x, acc0); acc1 = fmaf(ws, rv.y, acc1);
            wsum += ws;
        }
        y_lds[r][lane] = bf16rne(dv * acc0) | (bf16rne(dv * acc1) << 16);
        if (lane == 0) rs_lds[r] = dv * wsum;
    }
    __syncthreads();

    // --- MFMA: out_tile[16,256] = y @ WcT^T + rs*bc + b_gcn ---
    const int4* ya   = (const int4*)&y_lds[0][0];
    const int4* wct4 = (const int4*)wct;
    union { int4 v; frag_ab f; } a[4];
    #pragma unroll
    for (int kc = 0; kc < 4; ++kc)
        a[kc].v = ya[ln * 16 + kc * 4 + q];
    float rsv[4];
    #pragma unroll
    for (int r = 0; r < 4; ++r) rsv[r] = rs_lds[q * 4 + r];
    #pragma unroll
    for (int i = 0; i < 4; ++i) {
        int n0 = (w + 4 * i) * 16;
        union { int4 v; frag_ab f; } b[4];
        #pragma unroll
        for (int kc = 0; kc < 4; ++kc)
            b[kc].v = wct4[(n0 + ln) * 16 + kc * 4 + q];
        frag_cd accd = {0.f, 0.f, 0.f, 0.f};
        #pragma unroll
        for (int kc = 0; kc < 4; ++kc)
            accd = __builtin_amdgcn_mfma_f32_16x16x32_bf16(a[kc].f, b[kc].f, accd, 0, 0, 0);
        int n = n0 + ln;
        float bcv = bc[n], bgv = b_gcn[n];
        #pragma unroll
        for (int r = 0; r < 4; ++r) {
            int m = tile * 16 + q * 4 + r;
            out[m * HID + n] = accd[r] + rsv[r] * bcv + bgv;
        }
    }
}

extern "C" void kernel_launch(void* const* d_in, const int* in_sizes, int n_in,
                              void* d_out, int out_size, void* d_ws, size_t ws_size,
                              hipStream_t stream) {
    const float* x     = (const float*)d_in[0];
    const int*   ei    = (const int*)d_in[1];
    const float* Wp    = (const float*)d_in[2];
    const float* bp    = (const float*)d_in[3];
    const float* W_ih  = (const float*)d_in[4];
    const float* W_hh  = (const float*)d_in[5];
    const float* b_ih  = (const float*)d_in[6];
    const float* b_hh  = (const float*)d_in[7];
    const float* iw    = (const float*)d_in[8];
    const float* b_gcn = (const float*)d_in[9];
    float* out = (float*)d_out;

    char* ws = (char*)d_ws;
    int*      cursor = (int*)     (ws + 0);
    unsigned* wct    = (unsigned*)(ws + 40064);
    float*    bc     = (float*)   (ws + 105600);
    int*      bucket = (int*)     (ws + 106624);

    hipMemsetAsync(cursor, 0, N_NODES * sizeof(int), stream);

    k1_prep<<<NB1, 256, 0, stream>>>(ei, Wp, bp, W_ih, W_hh, b_ih, b_hh, iw,
                                     cursor, wct, bc, bucket);
    k2_agg_out<<<625, 256, 0, stream>>>(x, cursor, bucket, wct, bc, b_gcn, out);
}